// Round 1
// baseline (786.401 us; speedup 1.0000x reference)
//
#include <hip/hip_runtime.h>
#include <hip/hip_bf16.h>

#define EMB 64
#define DEGN 32
#define KSEL 16
#define EPSV 1e-8f

// One block (256 threads = 4 waves) per node.
//  wave 0: neighbors 0..15  of visual   -> LDS + sims
//  wave 1: neighbors 16..31 of visual
//  wave 2: neighbors 0..15  of text
//  wave 3: neighbors 16..31 of text
// Then rank-based top-16 selection (stable tie-break on lower index, matching
// jax.lax.top_k), then per-wave coalesced output writes.
__global__ __launch_bounds__(256) void graphsage_kernel(
    const int* __restrict__ nodes,
    const int* __restrict__ neigh,
    const float* __restrict__ emb_v,
    const float* __restrict__ emb_t,
    float* __restrict__ out,
    int n_nodes)
{
    const int n = blockIdx.x;
    if (n >= n_nodes) return;
    const int tid  = threadIdx.x;
    const int wave = tid >> 6;       // 0..3
    const int lane = tid & 63;       // dim index

    __shared__ float u_s[2][EMB];            // center embeddings
    __shared__ float unorm_s[2];             // ||u||
    __shared__ float nb_s[2][DEGN][EMB];     // raw neighbor features (16 KiB)
    __shared__ float sims_s[2][DEGN];
    __shared__ int   sel_s[2][DEGN];

    const int node = nodes[n];               // wave-uniform -> scalar load

    // ---- phase 1: center embeddings + norms ----
    if (wave < 2) {
        const int mod = wave;
        const float* __restrict__ e = (mod == 0) ? emb_v : emb_t;
        float u = e[(size_t)node * EMB + lane];
        u_s[mod][lane] = u;
        float s = u * u;
        #pragma unroll
        for (int off = 32; off >= 1; off >>= 1) s += __shfl_xor(s, off);
        if (lane == 0) unorm_s[mod] = sqrtf(s);
    }
    __syncthreads();

    // ---- phase 2: gather neighbors, compute cosine sims ----
    {
        const int mod   = wave >> 1;
        const int kbase = (wave & 1) * 16;
        const float* __restrict__ e = (mod == 0) ? emb_v : emb_t;
        // normalized center element (elementwise, matching the reference)
        const float un = u_s[mod][lane] / (unorm_s[mod] + EPSV);
        #pragma unroll
        for (int kk = 0; kk < 16; ++kk) {
            const int k   = kbase + kk;
            const int idx = neigh[n * DEGN + k];      // wave-uniform scalar load
            const float v = e[(size_t)idx * EMB + lane];
            nb_s[mod][k][lane] = v;
            // ||nb||^2 reduction
            float nsq = v * v;
            #pragma unroll
            for (int off = 32; off >= 1; off >>= 1) nsq += __shfl_xor(nsq, off);
            // elementwise normalize then dot (reference op order)
            const float vn = v / (sqrtf(nsq) + EPSV);
            float dp = un * vn;
            #pragma unroll
            for (int off = 32; off >= 1; off >>= 1) dp += __shfl_xor(dp, off);
            if (lane == 0) sims_s[mod][k] = dp;
        }
    }
    __syncthreads();

    // ---- phase 3: top-16 via rank (stable: lower index wins ties) ----
    if ((wave & 1) == 0 && lane < DEGN) {
        const int mod = wave >> 1;
        const int k = lane;
        const float sk = sims_s[mod][k];
        int rank = 0;
        #pragma unroll
        for (int j = 0; j < DEGN; ++j) {
            const float sj = sims_s[mod][j];
            rank += (sj > sk) || (sj == sk && j < k);
        }
        sel_s[mod][k] = (rank < KSEL) ? 1 : 0;
    }
    __syncthreads();

    // ---- phase 4: outputs ----
    // d_out layout: [u_v | u_t | v_agg | t_agg], each [n_nodes][EMB] row-major
    const size_t NOUT = (size_t)n_nodes * EMB;
    const size_t base = (size_t)n * EMB + lane;
    if (wave < 2) {
        const int mod = wave;            // aggregated outputs
        float s = 0.f;
        #pragma unroll
        for (int k = 0; k < DEGN; ++k) {
            if (sel_s[mod][k]) s += nb_s[mod][k][lane];
        }
        out[(size_t)(2 + mod) * NOUT + base] = s * (1.0f / KSEL);
    } else {
        const int mod = wave - 2;        // center passthrough outputs
        out[(size_t)mod * NOUT + base] = u_s[mod][lane];
    }
}

extern "C" void kernel_launch(void* const* d_in, const int* in_sizes, int n_in,
                              void* d_out, int out_size, void* d_ws, size_t ws_size,
                              hipStream_t stream) {
    const int*   nodes = (const int*)d_in[0];
    const int*   neigh = (const int*)d_in[1];
    const float* emb_v = (const float*)d_in[2];
    const float* emb_t = (const float*)d_in[3];
    float*       out   = (float*)d_out;
    const int n_nodes  = in_sizes[0];

    dim3 grid(n_nodes);
    dim3 block(256);
    graphsage_kernel<<<grid, block, 0, stream>>>(nodes, neigh, emb_v, emb_t, out, n_nodes);
}